// Round 3
// baseline (185.504 us; speedup 1.0000x reference)
//
#include <hip/hip_runtime.h>

// loss = mean_i max(0, 0.1 - (a[i] - b[i])), N = 33554432 fp32 per input.
// Bandwidth wall: 268.4 MB read, ~50% served from L3 (inputs = 256 MiB = L3).
// R2 analysis: not latency-bound (Little's law satisfied 8x over) -> fuse the
// finalize kernel (last-block pattern, deterministic fixed-order sum) to kill
// the second launch, and use 4096 blocks for smoother tail drain.

constexpr float MARGIN = 0.1f;

__device__ __forceinline__ float hinge4(float4 x, float4 y) {
    return fmaxf(0.0f, MARGIN - (x.x - y.x))
         + fmaxf(0.0f, MARGIN - (x.y - y.y))
         + fmaxf(0.0f, MARGIN - (x.z - y.z))
         + fmaxf(0.0f, MARGIN - (x.w - y.w));
}

__global__ void hinge_fused_kernel(const float* __restrict__ a,
                                   const float* __restrict__ b,
                                   float* __restrict__ out,
                                   float* __restrict__ partials,
                                   unsigned int* __restrict__ counter,
                                   int n4, int nblocks, float inv_n) {
    const float4* __restrict__ a4 = reinterpret_cast<const float4*>(a);
    const float4* __restrict__ b4 = reinterpret_cast<const float4*>(b);

    const int stride = gridDim.x * blockDim.x;
    int i = blockIdx.x * blockDim.x + threadIdx.x;

    float acc0 = 0.0f, acc1 = 0.0f, acc2 = 0.0f, acc3 = 0.0f;
    for (; i + 3 * stride < n4; i += 4 * stride) {
        float4 x0 = a4[i];
        float4 x1 = a4[i + stride];
        float4 x2 = a4[i + 2 * stride];
        float4 x3 = a4[i + 3 * stride];
        float4 y0 = b4[i];
        float4 y1 = b4[i + stride];
        float4 y2 = b4[i + 2 * stride];
        float4 y3 = b4[i + 3 * stride];
        acc0 += hinge4(x0, y0);
        acc1 += hinge4(x1, y1);
        acc2 += hinge4(x2, y2);
        acc3 += hinge4(x3, y3);
    }
    for (; i < n4; i += stride)
        acc0 += hinge4(a4[i], b4[i]);

    float acc = (acc0 + acc1) + (acc2 + acc3);

    // wave (64-lane) shuffle reduce
    #pragma unroll
    for (int off = 32; off > 0; off >>= 1)
        acc += __shfl_down(acc, off, 64);

    __shared__ float sdata[4];  // 256 threads = 4 waves
    const int lane = threadIdx.x & 63;
    const int wave = threadIdx.x >> 6;
    if (lane == 0) sdata[wave] = acc;
    __syncthreads();

    __shared__ int is_last;
    if (threadIdx.x == 0) {
        partials[blockIdx.x] = sdata[0] + sdata[1] + sdata[2] + sdata[3];
        __threadfence();  // release: partial visible before counter bump
        unsigned int old = atomicAdd(counter, 1u);  // device-scope by default
        is_last = (old == (unsigned int)(nblocks - 1));
    }
    __syncthreads();

    if (is_last) {
        __threadfence();  // acquire: all partials visible
        float facc = 0.0f;
        for (int j = threadIdx.x; j < nblocks; j += blockDim.x)
            facc += partials[j];  // fixed index order -> deterministic

        #pragma unroll
        for (int off = 32; off > 0; off >>= 1)
            facc += __shfl_down(facc, off, 64);

        __shared__ float fdata[4];
        if (lane == 0) fdata[wave] = facc;
        __syncthreads();
        if (threadIdx.x == 0)
            out[0] = (fdata[0] + fdata[1] + fdata[2] + fdata[3]) * inv_n;
    }
}

extern "C" void kernel_launch(void* const* d_in, const int* in_sizes, int n_in,
                              void* d_out, int out_size, void* d_ws, size_t ws_size,
                              hipStream_t stream) {
    const float* a = reinterpret_cast<const float*>(d_in[0]);  // alphas_part_max
    const float* b = reinterpret_cast<const float*>(d_in[1]);  // alphas_org
    float* out = reinterpret_cast<float*>(d_out);

    const int n = in_sizes[0];        // 33554432, divisible by 4
    const int n4 = n >> 2;

    const int block = 256;
    const int grid = 4096;            // 2 occupancy rounds -> smoother drain

    float* partials = reinterpret_cast<float*>(d_ws);
    unsigned int* counter = reinterpret_cast<unsigned int*>(
        reinterpret_cast<char*>(d_ws) + grid * sizeof(float));

    // Counter must be 0 at every replay (d_ws poisoned 0xAA once, never reset).
    hipMemsetAsync(counter, 0, sizeof(unsigned int), stream);

    hinge_fused_kernel<<<grid, block, 0, stream>>>(a, b, out, partials, counter,
                                                   n4, grid,
                                                   1.0f / static_cast<float>(n));
}

// Round 4
// 58.982 us; speedup vs baseline: 3.1451x; 3.1451x over previous
//
#include <hip/hip_runtime.h>

// loss = mean_i max(0, 0.1 - (a[i] - b[i])), N = 33554432 fp32 per input.
// R3 lesson: __threadfence on 8-XCD gfx950 = L2 writeback/invalidate per call
// (XCD L2s non-coherent) -> 4096 fences cost ~140us. Fuse WITHOUT fences:
// device-scope RELAXED atomics for partials (coherent, bypass dirty-L2),
// wave-local s_waitcnt vmcnt(0) to order store-before-counter-bump.

constexpr float MARGIN = 0.1f;

__device__ __forceinline__ float hinge4(float4 x, float4 y) {
    return fmaxf(0.0f, MARGIN - (x.x - y.x))
         + fmaxf(0.0f, MARGIN - (x.y - y.y))
         + fmaxf(0.0f, MARGIN - (x.z - y.z))
         + fmaxf(0.0f, MARGIN - (x.w - y.w));
}

__global__ void hinge_fused_kernel(const float* __restrict__ a,
                                   const float* __restrict__ b,
                                   float* __restrict__ out,
                                   float* __restrict__ partials,
                                   unsigned int* __restrict__ counter,
                                   int n4, int nblocks, float inv_n) {
    const float4* __restrict__ a4 = reinterpret_cast<const float4*>(a);
    const float4* __restrict__ b4 = reinterpret_cast<const float4*>(b);

    const int stride = gridDim.x * blockDim.x;
    int i = blockIdx.x * blockDim.x + threadIdx.x;

    float acc0 = 0.0f, acc1 = 0.0f, acc2 = 0.0f, acc3 = 0.0f;
    for (; i + 3 * stride < n4; i += 4 * stride) {
        float4 x0 = a4[i];
        float4 x1 = a4[i + stride];
        float4 x2 = a4[i + 2 * stride];
        float4 x3 = a4[i + 3 * stride];
        float4 y0 = b4[i];
        float4 y1 = b4[i + stride];
        float4 y2 = b4[i + 2 * stride];
        float4 y3 = b4[i + 3 * stride];
        acc0 += hinge4(x0, y0);
        acc1 += hinge4(x1, y1);
        acc2 += hinge4(x2, y2);
        acc3 += hinge4(x3, y3);
    }
    for (; i < n4; i += stride)
        acc0 += hinge4(a4[i], b4[i]);

    float acc = (acc0 + acc1) + (acc2 + acc3);

    // wave (64-lane) shuffle reduce
    #pragma unroll
    for (int off = 32; off > 0; off >>= 1)
        acc += __shfl_down(acc, off, 64);

    __shared__ float sdata[4];  // 256 threads = 4 waves
    const int lane = threadIdx.x & 63;
    const int wave = threadIdx.x >> 6;
    if (lane == 0) sdata[wave] = acc;
    __syncthreads();

    __shared__ int is_last;
    if (threadIdx.x == 0) {
        float p = sdata[0] + sdata[1] + sdata[2] + sdata[3];
        // Coherent (device-scope) store: bypasses the non-coherent L2 dirty
        // path, so NO buffer_wbl2 is needed to publish it.
        __hip_atomic_store(&partials[blockIdx.x], p, __ATOMIC_RELAXED,
                           __HIP_MEMORY_SCOPE_AGENT);
        // Order: partial store must complete (reach coherence point) before
        // the counter bump. Wave-local wait, no cache maintenance.
        asm volatile("s_waitcnt vmcnt(0)" ::: "memory");
        unsigned int old = __hip_atomic_fetch_add(counter, 1u, __ATOMIC_RELAXED,
                                                  __HIP_MEMORY_SCOPE_AGENT);
        is_last = (old == (unsigned int)(nblocks - 1));
    }
    __syncthreads();

    if (is_last) {
        float facc = 0.0f;
        for (int j = threadIdx.x; j < nblocks; j += blockDim.x) {
            // Coherent load: reads from the device coherence point, sees all
            // published partials. Fixed index order -> deterministic sum.
            facc += __hip_atomic_load(&partials[j], __ATOMIC_RELAXED,
                                      __HIP_MEMORY_SCOPE_AGENT);
        }

        #pragma unroll
        for (int off = 32; off > 0; off >>= 1)
            facc += __shfl_down(facc, off, 64);

        __shared__ float fdata[4];
        if (lane == 0) fdata[wave] = facc;
        __syncthreads();
        if (threadIdx.x == 0)
            out[0] = (fdata[0] + fdata[1] + fdata[2] + fdata[3]) * inv_n;
    }
}

extern "C" void kernel_launch(void* const* d_in, const int* in_sizes, int n_in,
                              void* d_out, int out_size, void* d_ws, size_t ws_size,
                              hipStream_t stream) {
    const float* a = reinterpret_cast<const float*>(d_in[0]);  // alphas_part_max
    const float* b = reinterpret_cast<const float*>(d_in[1]);  // alphas_org
    float* out = reinterpret_cast<float*>(d_out);

    const int n = in_sizes[0];        // 33554432, divisible by 4
    const int n4 = n >> 2;

    const int block = 256;
    const int grid = 2048;            // one full occupancy round (8 blocks/CU)

    float* partials = reinterpret_cast<float*>(d_ws);
    unsigned int* counter = reinterpret_cast<unsigned int*>(
        reinterpret_cast<char*>(d_ws) + grid * sizeof(float));

    // Counter must be 0 at every replay (d_ws poisoned once, never re-poisoned).
    hipMemsetAsync(counter, 0, sizeof(unsigned int), stream);

    hinge_fused_kernel<<<grid, block, 0, stream>>>(a, b, out, partials, counter,
                                                   n4, grid,
                                                   1.0f / static_cast<float>(n));
}

// Round 5
// 53.791 us; speedup vs baseline: 3.4486x; 1.0965x over previous
//
#include <hip/hip_runtime.h>

// loss = mean_i max(0, 0.1 - (a[i] - b[i])), N = 33554432 fp32 per input.
// R4 lessons: fusion (even fence-free) loses ~10us vs two kernels -> keep the
// R2 two-kernel shape. Remaining theory: static 1-round partitioning (grid
// 2048) leaves CUs idle behind HBM-miss straggler blocks (half the data is
// L3-resident and finishes ~2x faster). Fix: 8192 blocks (~4 rounds/CU,
// HW-dynamic dispatch), each thread straight-lines exactly 4 float4 pairs
// (n4 = 8192*256*4, no tail) -> finer quanta, balanced drain.

constexpr float MARGIN = 0.1f;

__device__ __forceinline__ float hinge4(float4 x, float4 y) {
    return fmaxf(0.0f, MARGIN - (x.x - y.x))
         + fmaxf(0.0f, MARGIN - (x.y - y.y))
         + fmaxf(0.0f, MARGIN - (x.z - y.z))
         + fmaxf(0.0f, MARGIN - (x.w - y.w));
}

__global__ void hinge_partial_kernel(const float* __restrict__ a,
                                     const float* __restrict__ b,
                                     float* __restrict__ partials,
                                     int n4) {
    const float4* __restrict__ a4 = reinterpret_cast<const float4*>(a);
    const float4* __restrict__ b4 = reinterpret_cast<const float4*>(b);

    const int stride = gridDim.x * blockDim.x;
    const int base = blockIdx.x * blockDim.x + threadIdx.x;

    float acc0 = 0.0f, acc1 = 0.0f, acc2 = 0.0f, acc3 = 0.0f;

    if (n4 == 4 * stride) {
        // Exact-fit fast path: straight-line, 8 independent loads in flight.
        float4 x0 = a4[base];
        float4 x1 = a4[base + stride];
        float4 x2 = a4[base + 2 * stride];
        float4 x3 = a4[base + 3 * stride];
        float4 y0 = b4[base];
        float4 y1 = b4[base + stride];
        float4 y2 = b4[base + 2 * stride];
        float4 y3 = b4[base + 3 * stride];
        acc0 = hinge4(x0, y0);
        acc1 = hinge4(x1, y1);
        acc2 = hinge4(x2, y2);
        acc3 = hinge4(x3, y3);
    } else {
        int i = base;
        for (; i + 3 * stride < n4; i += 4 * stride) {
            float4 x0 = a4[i];
            float4 x1 = a4[i + stride];
            float4 x2 = a4[i + 2 * stride];
            float4 x3 = a4[i + 3 * stride];
            float4 y0 = b4[i];
            float4 y1 = b4[i + stride];
            float4 y2 = b4[i + 2 * stride];
            float4 y3 = b4[i + 3 * stride];
            acc0 += hinge4(x0, y0);
            acc1 += hinge4(x1, y1);
            acc2 += hinge4(x2, y2);
            acc3 += hinge4(x3, y3);
        }
        for (; i < n4; i += stride)
            acc0 += hinge4(a4[i], b4[i]);
    }

    float acc = (acc0 + acc1) + (acc2 + acc3);

    // wave (64-lane) shuffle reduce
    #pragma unroll
    for (int off = 32; off > 0; off >>= 1)
        acc += __shfl_down(acc, off, 64);

    __shared__ float sdata[4];  // 256 threads = 4 waves
    const int lane = threadIdx.x & 63;
    const int wave = threadIdx.x >> 6;
    if (lane == 0) sdata[wave] = acc;
    __syncthreads();
    if (threadIdx.x == 0)
        partials[blockIdx.x] = sdata[0] + sdata[1] + sdata[2] + sdata[3];
}

__global__ void hinge_finalize_kernel(const float* __restrict__ partials,
                                      float* __restrict__ out,
                                      int nparts,
                                      float inv_n) {
    float acc = 0.0f;
    for (int i = threadIdx.x; i < nparts; i += blockDim.x)
        acc += partials[i];  // fixed index order -> deterministic

    #pragma unroll
    for (int off = 32; off > 0; off >>= 1)
        acc += __shfl_down(acc, off, 64);

    __shared__ float sdata[4];
    const int lane = threadIdx.x & 63;
    const int wave = threadIdx.x >> 6;
    if (lane == 0) sdata[wave] = acc;
    __syncthreads();
    if (threadIdx.x == 0)
        out[0] = (sdata[0] + sdata[1] + sdata[2] + sdata[3]) * inv_n;
}

extern "C" void kernel_launch(void* const* d_in, const int* in_sizes, int n_in,
                              void* d_out, int out_size, void* d_ws, size_t ws_size,
                              hipStream_t stream) {
    const float* a = reinterpret_cast<const float*>(d_in[0]);  // alphas_part_max
    const float* b = reinterpret_cast<const float*>(d_in[1]);  // alphas_org
    float* out = reinterpret_cast<float*>(d_out);
    float* partials = reinterpret_cast<float*>(d_ws);

    const int n = in_sizes[0];        // 33554432
    const int n4 = n >> 2;            // 8388608 = 8192 * 256 * 4

    const int block = 256;
    const int grid = 8192;            // ~4 rounds/CU, HW-dynamic load balance

    hinge_partial_kernel<<<grid, block, 0, stream>>>(a, b, partials, n4);
    hinge_finalize_kernel<<<1, block, 0, stream>>>(partials, out, grid,
                                                   1.0f / static_cast<float>(n));
}

// Round 6
// 49.587 us; speedup vs baseline: 3.7410x; 1.0848x over previous
//
#include <hip/hip_runtime.h>

// loss = mean_i max(0, 0.1 - (a[i] - b[i])), N = 33554432 fp32 per input.
//
// Final configuration (= R2, the measured best at 48.3 us):
//   - two kernels: grid-stride partial reduce (2048x256, unroll x4) +
//     1-block finalize. Fusion loses on this chip (R3: __threadfence =
//     per-block L2 writeback on 8-XCD gfx950, +137us; R4: fence-free
//     atomic handshake still +10us vs the extra launch).
//   - grid 2048 (8 blocks/CU): best measured; 8192 regressed (R5).
//
// Structural wall: 268.4 MB mandatory fp32 read. All traffic (L3-resident
// or not) shares the ~6.3 TB/s L2-miss/fabric path -> 42.7 us kernel floor
// + ~3 us finalize launch. 48.3 us total = ~97% of achievable.

constexpr float MARGIN = 0.1f;

__device__ __forceinline__ float hinge4(float4 x, float4 y) {
    return fmaxf(0.0f, MARGIN - (x.x - y.x))
         + fmaxf(0.0f, MARGIN - (x.y - y.y))
         + fmaxf(0.0f, MARGIN - (x.z - y.z))
         + fmaxf(0.0f, MARGIN - (x.w - y.w));
}

__global__ void hinge_partial_kernel(const float* __restrict__ a,
                                     const float* __restrict__ b,
                                     float* __restrict__ partials,
                                     int n4) {
    const float4* __restrict__ a4 = reinterpret_cast<const float4*>(a);
    const float4* __restrict__ b4 = reinterpret_cast<const float4*>(b);

    const int stride = gridDim.x * blockDim.x;
    int i = blockIdx.x * blockDim.x + threadIdx.x;

    float acc0 = 0.0f, acc1 = 0.0f, acc2 = 0.0f, acc3 = 0.0f;

    // 8 independent 16B loads in flight per iteration.
    for (; i + 3 * stride < n4; i += 4 * stride) {
        float4 x0 = a4[i];
        float4 x1 = a4[i + stride];
        float4 x2 = a4[i + 2 * stride];
        float4 x3 = a4[i + 3 * stride];
        float4 y0 = b4[i];
        float4 y1 = b4[i + stride];
        float4 y2 = b4[i + 2 * stride];
        float4 y3 = b4[i + 3 * stride];
        acc0 += hinge4(x0, y0);
        acc1 += hinge4(x1, y1);
        acc2 += hinge4(x2, y2);
        acc3 += hinge4(x3, y3);
    }
    for (; i < n4; i += stride)
        acc0 += hinge4(a4[i], b4[i]);

    float acc = (acc0 + acc1) + (acc2 + acc3);

    // wave (64-lane) shuffle reduce
    #pragma unroll
    for (int off = 32; off > 0; off >>= 1)
        acc += __shfl_down(acc, off, 64);

    __shared__ float sdata[4];  // 256 threads = 4 waves
    const int lane = threadIdx.x & 63;
    const int wave = threadIdx.x >> 6;
    if (lane == 0) sdata[wave] = acc;
    __syncthreads();
    if (threadIdx.x == 0)
        partials[blockIdx.x] = sdata[0] + sdata[1] + sdata[2] + sdata[3];
}

__global__ void hinge_finalize_kernel(const float* __restrict__ partials,
                                      float* __restrict__ out,
                                      int nparts,
                                      float inv_n) {
    float acc = 0.0f;
    for (int i = threadIdx.x; i < nparts; i += blockDim.x)
        acc += partials[i];  // fixed index order -> deterministic

    #pragma unroll
    for (int off = 32; off > 0; off >>= 1)
        acc += __shfl_down(acc, off, 64);

    __shared__ float sdata[4];
    const int lane = threadIdx.x & 63;
    const int wave = threadIdx.x >> 6;
    if (lane == 0) sdata[wave] = acc;
    __syncthreads();
    if (threadIdx.x == 0)
        out[0] = (sdata[0] + sdata[1] + sdata[2] + sdata[3]) * inv_n;
}

extern "C" void kernel_launch(void* const* d_in, const int* in_sizes, int n_in,
                              void* d_out, int out_size, void* d_ws, size_t ws_size,
                              hipStream_t stream) {
    const float* a = reinterpret_cast<const float*>(d_in[0]);  // alphas_part_max
    const float* b = reinterpret_cast<const float*>(d_in[1]);  // alphas_org
    float* out = reinterpret_cast<float*>(d_out);
    float* partials = reinterpret_cast<float*>(d_ws);

    const int n = in_sizes[0];        // 33554432, divisible by 4
    const int n4 = n >> 2;

    const int block = 256;
    const int grid = 2048;            // 8 blocks/CU; each thread: 16 float4 iters

    hinge_partial_kernel<<<grid, block, 0, stream>>>(a, b, partials, n4);
    hinge_finalize_kernel<<<1, block, 0, stream>>>(partials, out, grid,
                                                   1.0f / static_cast<float>(n));
}